// Round 9
// baseline (509.513 us; speedup 1.0000x reference)
//
#include <hip/hip_runtime.h>
#include <math.h>

#define NN 100000
#define NE 1600000
#define F_IN 602
#define H1 8
#define C1 8
#define F_MID 64   // H1*C1
#define NC 41
#define NEG_SLOPE 0.2f
#define WT_LD 640  // padded K for bf16 W1-transposed

#define LRELU(x) fmaxf((x), NEG_SLOPE * (x))

typedef __attribute__((ext_vector_type(8))) short short8;
typedef __attribute__((ext_vector_type(4))) float f32x4;

__device__ inline unsigned short f2bf(float f) {
    unsigned u = __builtin_bit_cast(unsigned, f);
    unsigned r = (u + 0x7FFFu + ((u >> 16) & 1u)) >> 16;
    return (unsigned short)r;
}

__device__ inline short8 load_cvt8(const float* __restrict__ p) {
    float2 v0 = *(const float2*)(p);
    float2 v1 = *(const float2*)(p + 2);
    float2 v2 = *(const float2*)(p + 4);
    float2 v3 = *(const float2*)(p + 6);
    short8 r;
    r[0] = (short)f2bf(v0.x); r[1] = (short)f2bf(v0.y);
    r[2] = (short)f2bf(v1.x); r[3] = (short)f2bf(v1.y);
    r[4] = (short)f2bf(v2.x); r[5] = (short)f2bf(v2.y);
    r[6] = (short)f2bf(v3.x); r[7] = (short)f2bf(v3.y);
    return r;
}

// ---------------- zero deg+cursor ----------------
__global__ void zero_kernel(int4* __restrict__ p, int n4)
{
    int i = blockIdx.x * blockDim.x + threadIdx.x;
    if (i < n4) p[i] = make_int4(0, 0, 0, 0);
}

// ---------------- W1 -> bf16 transposed padded [64][640] ----------------
__global__ void prep_wt_kernel(const float* __restrict__ W, unsigned short* __restrict__ Wt)
{
    int idx = blockIdx.x * blockDim.x + threadIdx.x;
    if (idx >= F_MID * WT_LD) return;
    int col = idx / WT_LD, k = idx % WT_LD;
    Wt[idx] = (k < F_IN) ? f2bf(W[k * F_MID + col]) : (unsigned short)0;
}

// ---------------- GEMM1 (MFMA bf16, no LDS, no barriers): h1 = x @ W1 ----------------
// 256 thr = 4 independent waves; wave computes 32 rows x 64 cols.
// A frags loaded directly from x (8 consecutive k per lane -> line-coalesced),
// B frags directly from L2-resident Wt.
__global__ __launch_bounds__(256) void gemm1_mfma(
    const float* __restrict__ x, const unsigned short* __restrict__ Wt,
    float* __restrict__ h, int N)
{
    int t = threadIdx.x;
    int lane = t & 63;
    int w = t >> 6;
    int l16 = lane & 15, lg = lane >> 4;
    int row0 = blockIdx.x * 128 + w * 32;

    int r0 = row0 + l16;
    int r1 = row0 + 16 + l16;
    const float* a0 = x + (size_t)(r0 < N ? r0 : 0) * F_IN + lg * 8;
    const float* a1 = x + (size_t)(r1 < N ? r1 : 0) * F_IN + lg * 8;
    const unsigned short* bp = Wt + (size_t)l16 * WT_LD + lg * 8;

    f32x4 acc[2][4] = {};

    #pragma unroll
    for (int kt = 0; kt < 9; ++kt) {            // k 0..575, branch-free
        int k0 = kt * 64;
        #pragma unroll
        for (int ks = 0; ks < 2; ++ks) {
            int ko = k0 + ks * 32;
            short8 af0 = load_cvt8(a0 + ko);
            short8 af1 = load_cvt8(a1 + ko);
            short8 bf[4];
            #pragma unroll
            for (int n = 0; n < 4; ++n)
                bf[n] = *(const short8*)(bp + (size_t)n * 16 * WT_LD + ko);
            #pragma unroll
            for (int n = 0; n < 4; ++n) {
                acc[0][n] = __builtin_amdgcn_mfma_f32_16x16x32_bf16(af0, bf[n], acc[0][n], 0, 0, 0);
                acc[1][n] = __builtin_amdgcn_mfma_f32_16x16x32_bf16(af1, bf[n], acc[1][n], 0, 0, 0);
            }
        }
    }
    {                                            // tail k0=576 (ks=0 only), guarded
        const int k0 = 576;
        float v0[8], v1[8];
        #pragma unroll
        for (int i = 0; i < 8; ++i) {
            int k = k0 + lg * 8 + i;             // true k index
            bool ok = k < F_IN;
            v0[i] = ok ? a0[k0 + i] : 0.f;
            v1[i] = ok ? a1[k0 + i] : 0.f;
        }
        short8 af0, af1;
        #pragma unroll
        for (int i = 0; i < 8; ++i) { af0[i] = (short)f2bf(v0[i]); af1[i] = (short)f2bf(v1[i]); }
        short8 bf[4];
        #pragma unroll
        for (int n = 0; n < 4; ++n)
            bf[n] = *(const short8*)(bp + (size_t)n * 16 * WT_LD + k0);  // Wt zero-padded past 601
        #pragma unroll
        for (int n = 0; n < 4; ++n) {
            acc[0][n] = __builtin_amdgcn_mfma_f32_16x16x32_bf16(af0, bf[n], acc[0][n], 0, 0, 0);
            acc[1][n] = __builtin_amdgcn_mfma_f32_16x16x32_bf16(af1, bf[n], acc[1][n], 0, 0, 0);
        }
    }

    // epilogue: C/D layout col=lane&15, row=(lane>>4)*4+reg
    #pragma unroll
    for (int m = 0; m < 2; ++m) {
        #pragma unroll
        for (int r = 0; r < 4; ++r) {
            int row = row0 + m * 16 + lg * 4 + r;
            if (row < N) {
                #pragma unroll
                for (int n = 0; n < 4; ++n)
                    h[(size_t)row * F_MID + n * 16 + l16] = acc[m][n][r];
            }
        }
    }
}

// ---------------- attention coefficients layer 1 ----------------
__global__ void attn1_kernel(const float* __restrict__ h,
                             const float* __restrict__ attS,
                             const float* __restrict__ attD,
                             float* __restrict__ asrc, float* __restrict__ adst, int N)
{
    int idx = blockIdx.x * blockDim.x + threadIdx.x;   // n*8 + head
    if (idx >= N * H1) return;
    int n = idx >> 3, hh = idx & 7;
    float s = 0.f, d = 0.f;
    #pragma unroll
    for (int c = 0; c < C1; ++c) {
        float v = h[n * F_MID + hh * C1 + c];
        s += v * attS[hh * C1 + c];
        d += v * attD[hh * C1 + c];
    }
    asrc[idx] = s;
    adst[idx] = d;
}

// ---------------- CSR build ----------------
__global__ void deg_kernel(const int* __restrict__ dst, int* __restrict__ deg, int E)
{
    int e = blockIdx.x * blockDim.x + threadIdx.x;
    if (e < E) atomicAdd(&deg[dst[e]], 1);
}

// hierarchical scan: 1024 elements per block (64 threads x 16)
__global__ void scan1_kernel(const int* __restrict__ deg, int* __restrict__ bsum, int N)
{
    int b = blockIdx.x, t = threadIdx.x;
    int base = b * 1024 + t * 16;
    int s = 0;
    #pragma unroll
    for (int i = 0; i < 16; ++i) { int idx = base + i; if (idx < N) s += deg[idx]; }
    #pragma unroll
    for (int o = 32; o > 0; o >>= 1) s += __shfl_down(s, o);
    if (t == 0) bsum[b] = s;
}

__global__ void scan2_kernel(const int* __restrict__ bsum, int* __restrict__ boff,
                             int nb, int* __restrict__ offs, int N, int E)
{
    __shared__ int buf[128];
    int t = threadIdx.x;
    int v = (t < nb) ? bsum[t] : 0;
    buf[t] = v;
    __syncthreads();
    for (int o = 1; o < 128; o <<= 1) {
        int u = (t >= o) ? buf[t - o] : 0;
        __syncthreads();
        buf[t] += u;
        __syncthreads();
    }
    if (t < nb) boff[t] = buf[t] - v;    // exclusive
    if (t == 0) offs[N] = E;
}

__global__ void scan3_kernel(const int* __restrict__ deg, const int* __restrict__ boff,
                             int* __restrict__ offs, int N)
{
    int b = blockIdx.x, t = threadIdx.x;
    int base = b * 1024 + t * 16;
    int loc[16];
    int s = 0;
    #pragma unroll
    for (int i = 0; i < 16; ++i) {
        int idx = base + i;
        loc[i] = (idx < N) ? deg[idx] : 0;
        s += loc[i];
    }
    int inc = s;
    #pragma unroll
    for (int o = 1; o < 64; o <<= 1) {
        int u = __shfl_up(inc, o);
        if (t >= o) inc += u;
    }
    int run = inc - s + boff[b];
    #pragma unroll
    for (int i = 0; i < 16; ++i) {
        int idx = base + i;
        if (idx < N) offs[idx] = run;
        run += loc[i];
    }
}

__global__ void scatter_kernel(const int* __restrict__ src, const int* __restrict__ dst,
                               const int* __restrict__ offs, int* __restrict__ cursor,
                               int* __restrict__ srcs, int E)
{
    int e = blockIdx.x * blockDim.x + threadIdx.x;
    if (e < E) {
        int d = dst[e];
        int pos = offs[d] + atomicAdd(&cursor[d], 1);
        srcs[pos] = src[e];
    }
}

// ------- layer-1 aggregation + ELU: one wave per node, online softmax, 4-edge batches -------
__global__ void agg1_kernel(const int* __restrict__ offs, const int* __restrict__ srcs,
                            const float* __restrict__ h1,
                            const float* __restrict__ asrc, const float* __restrict__ adst,
                            const float* __restrict__ b1,
                            float* __restrict__ out1, int N)
{
    int wave = (blockIdx.x * blockDim.x + threadIdx.x) >> 6;
    int lane = threadIdx.x & 63;
    if (wave >= N) return;
    int n = wave;
    int hh = lane >> 3;                 // head
    int beg = offs[n], end = offs[n + 1];
    float ad = adst[n * H1 + hh];

    float m = -INFINITY, den = 0.f, acc = 0.f;
    int i = beg;
    for (; i + 4 <= end; i += 4) {
        int s0 = srcs[i], s1 = srcs[i + 1], s2 = srcs[i + 2], s3 = srcs[i + 3];
        float a0 = asrc[s0 * H1 + hh], a1 = asrc[s1 * H1 + hh];
        float a2 = asrc[s2 * H1 + hh], a3 = asrc[s3 * H1 + hh];
        float v0 = h1[s0 * F_MID + lane], v1 = h1[s1 * F_MID + lane];
        float v2 = h1[s2 * F_MID + lane], v3 = h1[s3 * F_MID + lane];
        float e0 = LRELU(a0 + ad), e1 = LRELU(a1 + ad);
        float e2 = LRELU(a2 + ad), e3 = LRELU(a3 + ad);
        float m4 = fmaxf(fmaxf(e0, e1), fmaxf(e2, e3));
        float mn = fmaxf(m, m4);
        float sc = __expf(m - mn);
        float p0 = __expf(e0 - mn), p1 = __expf(e1 - mn);
        float p2 = __expf(e2 - mn), p3 = __expf(e3 - mn);
        den = den * sc + ((p0 + p1) + (p2 + p3));
        acc = acc * sc + ((p0 * v0 + p1 * v1) + (p2 * v2 + p3 * v3));
        m = mn;
    }
    for (; i < end; ++i) {
        int s = srcs[i];
        float e = LRELU(asrc[s * H1 + hh] + ad);
        float hv = h1[s * F_MID + lane];
        float mn = fmaxf(m, e);
        float sc = __expf(m - mn);
        float p  = __expf(e - mn);
        den = den * sc + p;
        acc = acc * sc + p * hv;
        m = mn;
    }
    float inv = 1.f / (den + 1e-16f);
    float v = acc * inv + b1[lane];
    out1[n * F_MID + lane] = v > 0.f ? v : expm1f(v);   // ELU
}

// ---------------- GEMM2: h2 = out1 @ W2  [N,64] x [64,41] ----------------
__global__ __launch_bounds__(256) void gemm2_kernel(
    const float* __restrict__ out1, const float* __restrict__ W2,
    float* __restrict__ h2, int N)
{
    __shared__ float ws[F_MID * NC];
    for (int i = threadIdx.x; i < F_MID * NC; i += 256) ws[i] = W2[i];
    __syncthreads();
    int idx = blockIdx.x * blockDim.x + threadIdx.x;
    if (idx >= N * NC) return;
    int n = idx / NC, j = idx % NC;
    const float* row = out1 + n * F_MID;
    float acc = 0.f;
    #pragma unroll
    for (int k = 0; k < F_MID; ++k) acc += row[k] * ws[k * NC + j];
    h2[idx] = acc;
}

__global__ void attn2_kernel(const float* __restrict__ h2,
                             const float* __restrict__ attS,
                             const float* __restrict__ attD,
                             float* __restrict__ asrc, float* __restrict__ adst, int N)
{
    int n = blockIdx.x * blockDim.x + threadIdx.x;
    if (n >= N) return;
    float s = 0.f, d = 0.f;
    #pragma unroll
    for (int j = 0; j < NC; ++j) {
        float v = h2[n * NC + j];
        s += v * attS[j];
        d += v * attD[j];
    }
    asrc[n] = s;
    adst[n] = d;
}

// ------- layer-2 aggregation + log_softmax: one wave per node, online softmax -------
__global__ void agg2_kernel(const int* __restrict__ offs, const int* __restrict__ srcs,
                            const float* __restrict__ h2,
                            const float* __restrict__ asrc, const float* __restrict__ adst,
                            const float* __restrict__ b2,
                            float* __restrict__ out, int N)
{
    int wave = (blockIdx.x * blockDim.x + threadIdx.x) >> 6;
    int lane = threadIdx.x & 63;
    if (wave >= N) return;
    int n = wave;
    int beg = offs[n], end = offs[n + 1];
    float ad = adst[n];
    bool act = lane < NC;

    float m = -INFINITY, den = 0.f, acc = 0.f;
    int i = beg;
    for (; i + 4 <= end; i += 4) {
        int s0 = srcs[i], s1 = srcs[i + 1], s2 = srcs[i + 2], s3 = srcs[i + 3];
        float a0 = asrc[s0], a1 = asrc[s1], a2 = asrc[s2], a3 = asrc[s3];
        float v0 = act ? h2[s0 * NC + lane] : 0.f;
        float v1 = act ? h2[s1 * NC + lane] : 0.f;
        float v2 = act ? h2[s2 * NC + lane] : 0.f;
        float v3 = act ? h2[s3 * NC + lane] : 0.f;
        float e0 = LRELU(a0 + ad), e1 = LRELU(a1 + ad);
        float e2 = LRELU(a2 + ad), e3 = LRELU(a3 + ad);
        float m4 = fmaxf(fmaxf(e0, e1), fmaxf(e2, e3));
        float mn = fmaxf(m, m4);
        float sc = __expf(m - mn);
        float p0 = __expf(e0 - mn), p1 = __expf(e1 - mn);
        float p2 = __expf(e2 - mn), p3 = __expf(e3 - mn);
        den = den * sc + ((p0 + p1) + (p2 + p3));
        acc = acc * sc + ((p0 * v0 + p1 * v1) + (p2 * v2 + p3 * v3));
        m = mn;
    }
    for (; i < end; ++i) {
        int s = srcs[i];
        float e = LRELU(asrc[s] + ad);
        float hv = act ? h2[s * NC + lane] : 0.f;
        float mn = fmaxf(m, e);
        float sc = __expf(m - mn);
        float p  = __expf(e - mn);
        den = den * sc + p;
        acc = acc * sc + p * hv;
        m = mn;
    }
    float inv = 1.f / (den + 1e-16f);
    float v = act ? acc * inv + b2[lane] : -INFINITY;
    float mm = v;
    #pragma unroll
    for (int o = 32; o > 0; o >>= 1) mm = fmaxf(mm, __shfl_xor(mm, o));
    float ex = act ? __expf(v - mm) : 0.f;
    float S = ex;
    #pragma unroll
    for (int o = 32; o > 0; o >>= 1) S += __shfl_xor(S, o);
    if (act) out[n * NC + lane] = v - mm - logf(S);
}

// ---------------- launch ----------------
extern "C" void kernel_launch(void* const* d_in, const int* in_sizes, int n_in,
                              void* d_out, int out_size, void* d_ws, size_t ws_size,
                              hipStream_t stream)
{
    const float* x     = (const float*)d_in[0];
    const int*   ei    = (const int*)  d_in[1];
    const float* W1    = (const float*)d_in[2];
    const float* attS1 = (const float*)d_in[3];
    const float* attD1 = (const float*)d_in[4];
    const float* b1    = (const float*)d_in[5];
    const float* W2    = (const float*)d_in[6];
    const float* attS2 = (const float*)d_in[7];
    const float* attD2 = (const float*)d_in[8];
    const float* b2    = (const float*)d_in[9];
    float* out = (float*)d_out;

    const int N = NN, E = NE;
    const int* src = ei;        // edge_index row 0
    const int* dst = ei + E;    // edge_index row 1

    char* p = (char*)d_ws;
    auto alloc = [&](size_t bytes) { char* r = p; p += (bytes + 255) & ~255ull; return r; };
    float* h1    = (float*)alloc((size_t)N * F_MID * 4);
    float* asrc1 = (float*)alloc((size_t)N * H1 * 4);
    float* adst1 = (float*)alloc((size_t)N * H1 * 4);
    float* out1  = (float*)alloc((size_t)N * F_MID * 4);
    float* h2    = (float*)alloc((size_t)N * NC * 4);
    float* asrc2 = (float*)alloc((size_t)N * 4);
    float* adst2 = (float*)alloc((size_t)N * 4);
    int*   deg   = (int*)alloc((size_t)2 * N * 4);    // deg + cursor contiguous
    int*   cursor= deg + N;
    int*   offs  = (int*)alloc((size_t)(N + 1) * 4);
    int*   srcs  = (int*)alloc((size_t)E * 4);
    unsigned short* Wt = (unsigned short*)alloc((size_t)F_MID * WT_LD * 2);
    const int NB = (N + 1023) / 1024;                 // 98 scan blocks
    int*   bsum  = (int*)alloc((size_t)NB * 4);
    int*   boff  = (int*)alloc((size_t)NB * 4);

    const int n4 = (2 * N) / 4;
    zero_kernel<<<(n4 + 255) / 256, 256, 0, stream>>>((int4*)deg, n4);

    prep_wt_kernel<<<(F_MID * WT_LD + 255) / 256, 256, 0, stream>>>(W1, Wt);
    gemm1_mfma<<<(N + 127) / 128, 256, 0, stream>>>(x, Wt, h1, N);
    attn1_kernel<<<(N * H1 + 255) / 256, 256, 0, stream>>>(h1, attS1, attD1, asrc1, adst1, N);
    deg_kernel<<<(E + 255) / 256, 256, 0, stream>>>(dst, deg, E);
    scan1_kernel<<<NB, 64, 0, stream>>>(deg, bsum, N);
    scan2_kernel<<<1, 128, 0, stream>>>(bsum, boff, NB, offs, N, E);
    scan3_kernel<<<NB, 64, 0, stream>>>(deg, boff, offs, N);
    scatter_kernel<<<(E + 255) / 256, 256, 0, stream>>>(src, dst, offs, cursor, srcs, E);
    agg1_kernel<<<(N * 64 + 255) / 256, 256, 0, stream>>>(offs, srcs, h1, asrc1, adst1, b1, out1, N);
    gemm2_kernel<<<(N * NC + 255) / 256, 256, 0, stream>>>(out1, W2, h2, N);
    attn2_kernel<<<(N + 255) / 256, 256, 0, stream>>>(h2, attS2, attD2, asrc2, adst2, N);
    agg2_kernel<<<(N * 64 + 255) / 256, 256, 0, stream>>>(offs, srcs, h2, asrc2, adst2, b2, out, N);
}

// Round 10
// 470.340 us; speedup vs baseline: 1.0833x; 1.0833x over previous
//
#include <hip/hip_runtime.h>
#include <math.h>

#define NN 100000
#define NE 1600000
#define F_IN 602
#define H1 8
#define C1 8
#define F_MID 64   // H1*C1
#define NC 41
#define NEG_SLOPE 0.2f
#define WT_LD 640  // padded K for bf16 W1-transposed

#define LRELU(x) fmaxf((x), NEG_SLOPE * (x))

typedef __attribute__((ext_vector_type(8))) short short8;
typedef __attribute__((ext_vector_type(4))) float f32x4;

__device__ inline unsigned short f2bf(float f) {
    unsigned u = __builtin_bit_cast(unsigned, f);
    unsigned r = (u + 0x7FFFu + ((u >> 16) & 1u)) >> 16;
    return (unsigned short)r;
}

// ---------------- zero deg+cursor ----------------
__global__ void zero_kernel(int4* __restrict__ p, int n4)
{
    int i = blockIdx.x * blockDim.x + threadIdx.x;
    if (i < n4) p[i] = make_int4(0, 0, 0, 0);
}

// ---------------- W1 -> bf16 transposed padded [64][640] ----------------
__global__ void prep_wt_kernel(const float* __restrict__ W, unsigned short* __restrict__ Wt)
{
    int idx = blockIdx.x * blockDim.x + threadIdx.x;
    if (idx >= F_MID * WT_LD) return;
    int col = idx / WT_LD, k = idx % WT_LD;
    Wt[idx] = (k < F_IN) ? f2bf(W[k * F_MID + col]) : (unsigned short)0;
}

// ---- GEMM1 (MFMA bf16, BM=64, BK=32, reg-prefetch): h1 = x @ W1 [N,602]x[602,64] ----
// 1563 blocks (~6/CU, ~24 waves/CU) to hide L3/L2 latency via TLP.
// Wave w computes rows w*16..w*16+15 x all 64 cols: 1 afrag x 4 bfrags = 4 MFMA/tile.
__global__ __launch_bounds__(256) void gemm1_mfma(
    const float* __restrict__ x, const unsigned short* __restrict__ Wt,
    float* __restrict__ h, int N)
{
    __shared__ unsigned short As[64][40];  // stride 80B -> <=2-way conflicts
    __shared__ unsigned short Bs[64][40];

    int t = threadIdx.x;
    int lane = t & 63;
    int w = t >> 6;
    int l16 = lane & 15, lg = lane >> 4;
    int n0 = blockIdx.x * 64;

    // A staging: 4 threads/row, 8 consecutive floats each
    int arow = t >> 2, aseg = t & 3;
    int grow = n0 + arow;
    const float* xrow = x + (size_t)(grow < N ? grow : 0) * F_IN + aseg * 8;
    // B staging: 4 threads/col, 8 consecutive k each (Wt padded/zeroed to 640)
    int bcol = t >> 2;
    const unsigned short* wrow = Wt + (size_t)bcol * WT_LD + aseg * 8;

    f32x4 acc[4] = {};
    float2 av[4];
    uint4  bv;

    // prologue: tile 0 (branch-free)
    #pragma unroll
    for (int i = 0; i < 4; ++i) av[i] = *(const float2*)(xrow + i * 2);
    bv = *(const uint4*)(wrow);

    for (int kt = 0; kt < 19; ++kt) {
        __syncthreads();   // previous tile's frag reads complete
        {
            unsigned short tmp[8];
            #pragma unroll
            for (int i = 0; i < 4; ++i) {
                tmp[i * 2]     = f2bf(av[i].x);
                tmp[i * 2 + 1] = f2bf(av[i].y);
            }
            *(uint4*)(&As[arow][aseg * 8]) = *(uint4*)tmp;
            *(uint4*)(&Bs[bcol][aseg * 8]) = bv;
        }
        __syncthreads();   // LDS ready

        // issue next tile's loads (hide under frag reads + MFMA)
        if (kt < 18) {
            int k0 = (kt + 1) * 32;
            if (kt + 1 < 18) {
                #pragma unroll
                for (int i = 0; i < 4; ++i) av[i] = *(const float2*)(xrow + k0 + i * 2);
            } else {        // tail tile: k 576..607, valid < 602
                #pragma unroll
                for (int i = 0; i < 4; ++i) {
                    int k = k0 + aseg * 8 + i * 2;
                    float a = (k < F_IN)     ? xrow[k0 + i * 2]     : 0.f;
                    float b = (k + 1 < F_IN) ? xrow[k0 + i * 2 + 1] : 0.f;
                    av[i] = make_float2(a, b);
                }
            }
            bv = *(const uint4*)(wrow + k0);
        }

        short8 afrag = *(const short8*)(&As[w * 16 + l16][lg * 8]);
        short8 bfrag[4];
        #pragma unroll
        for (int n = 0; n < 4; ++n)
            bfrag[n] = *(const short8*)(&Bs[n * 16 + l16][lg * 8]);
        #pragma unroll
        for (int n = 0; n < 4; ++n)
            acc[n] = __builtin_amdgcn_mfma_f32_16x16x32_bf16(afrag, bfrag[n], acc[n], 0, 0, 0);
    }

    // epilogue: C/D layout col=lane&15, row=(lane>>4)*4+reg
    #pragma unroll
    for (int r = 0; r < 4; ++r) {
        int row = n0 + w * 16 + lg * 4 + r;
        if (row < N) {
            #pragma unroll
            for (int n = 0; n < 4; ++n)
                h[(size_t)row * F_MID + n * 16 + l16] = acc[n][r];
        }
    }
}

// ---------------- attention coefficients layer 1 ----------------
__global__ void attn1_kernel(const float* __restrict__ h,
                             const float* __restrict__ attS,
                             const float* __restrict__ attD,
                             float* __restrict__ asrc, float* __restrict__ adst, int N)
{
    int idx = blockIdx.x * blockDim.x + threadIdx.x;   // n*8 + head
    if (idx >= N * H1) return;
    int n = idx >> 3, hh = idx & 7;
    float s = 0.f, d = 0.f;
    #pragma unroll
    for (int c = 0; c < C1; ++c) {
        float v = h[n * F_MID + hh * C1 + c];
        s += v * attS[hh * C1 + c];
        d += v * attD[hh * C1 + c];
    }
    asrc[idx] = s;
    adst[idx] = d;
}

// ---------------- CSR build ----------------
__global__ void deg_kernel(const int* __restrict__ dst, int* __restrict__ deg, int E)
{
    int e = blockIdx.x * blockDim.x + threadIdx.x;
    if (e < E) atomicAdd(&deg[dst[e]], 1);
}

// hierarchical scan: 1024 elements per block (64 threads x 16)
__global__ void scan1_kernel(const int* __restrict__ deg, int* __restrict__ bsum, int N)
{
    int b = blockIdx.x, t = threadIdx.x;
    int base = b * 1024 + t * 16;
    int s = 0;
    #pragma unroll
    for (int i = 0; i < 16; ++i) { int idx = base + i; if (idx < N) s += deg[idx]; }
    #pragma unroll
    for (int o = 32; o > 0; o >>= 1) s += __shfl_down(s, o);
    if (t == 0) bsum[b] = s;
}

__global__ void scan2_kernel(const int* __restrict__ bsum, int* __restrict__ boff,
                             int nb, int* __restrict__ offs, int N, int E)
{
    __shared__ int buf[128];
    int t = threadIdx.x;
    int v = (t < nb) ? bsum[t] : 0;
    buf[t] = v;
    __syncthreads();
    for (int o = 1; o < 128; o <<= 1) {
        int u = (t >= o) ? buf[t - o] : 0;
        __syncthreads();
        buf[t] += u;
        __syncthreads();
    }
    if (t < nb) boff[t] = buf[t] - v;    // exclusive
    if (t == 0) offs[N] = E;
}

__global__ void scan3_kernel(const int* __restrict__ deg, const int* __restrict__ boff,
                             int* __restrict__ offs, int N)
{
    int b = blockIdx.x, t = threadIdx.x;
    int base = b * 1024 + t * 16;
    int loc[16];
    int s = 0;
    #pragma unroll
    for (int i = 0; i < 16; ++i) {
        int idx = base + i;
        loc[i] = (idx < N) ? deg[idx] : 0;
        s += loc[i];
    }
    int inc = s;
    #pragma unroll
    for (int o = 1; o < 64; o <<= 1) {
        int u = __shfl_up(inc, o);
        if (t >= o) inc += u;
    }
    int run = inc - s + boff[b];
    #pragma unroll
    for (int i = 0; i < 16; ++i) {
        int idx = base + i;
        if (idx < N) offs[idx] = run;
        run += loc[i];
    }
}

__global__ void scatter_kernel(const int* __restrict__ src, const int* __restrict__ dst,
                               const int* __restrict__ offs, int* __restrict__ cursor,
                               int* __restrict__ srcs, int E)
{
    int e = blockIdx.x * blockDim.x + threadIdx.x;
    if (e < E) {
        int d = dst[e];
        int pos = offs[d] + atomicAdd(&cursor[d], 1);
        srcs[pos] = src[e];
    }
}

// ------- layer-1 aggregation + ELU: one wave per node, online softmax, 4-edge batches -------
__global__ void agg1_kernel(const int* __restrict__ offs, const int* __restrict__ srcs,
                            const float* __restrict__ h1,
                            const float* __restrict__ asrc, const float* __restrict__ adst,
                            const float* __restrict__ b1,
                            float* __restrict__ out1, int N)
{
    int wave = (blockIdx.x * blockDim.x + threadIdx.x) >> 6;
    int lane = threadIdx.x & 63;
    if (wave >= N) return;
    int n = wave;
    int hh = lane >> 3;                 // head
    int beg = offs[n], end = offs[n + 1];
    float ad = adst[n * H1 + hh];

    float m = -INFINITY, den = 0.f, acc = 0.f;
    int i = beg;
    for (; i + 4 <= end; i += 4) {
        int s0 = srcs[i], s1 = srcs[i + 1], s2 = srcs[i + 2], s3 = srcs[i + 3];
        float a0 = asrc[s0 * H1 + hh], a1 = asrc[s1 * H1 + hh];
        float a2 = asrc[s2 * H1 + hh], a3 = asrc[s3 * H1 + hh];
        float v0 = h1[s0 * F_MID + lane], v1 = h1[s1 * F_MID + lane];
        float v2 = h1[s2 * F_MID + lane], v3 = h1[s3 * F_MID + lane];
        float e0 = LRELU(a0 + ad), e1 = LRELU(a1 + ad);
        float e2 = LRELU(a2 + ad), e3 = LRELU(a3 + ad);
        float m4 = fmaxf(fmaxf(e0, e1), fmaxf(e2, e3));
        float mn = fmaxf(m, m4);
        float sc = __expf(m - mn);
        float p0 = __expf(e0 - mn), p1 = __expf(e1 - mn);
        float p2 = __expf(e2 - mn), p3 = __expf(e3 - mn);
        den = den * sc + ((p0 + p1) + (p2 + p3));
        acc = acc * sc + ((p0 * v0 + p1 * v1) + (p2 * v2 + p3 * v3));
        m = mn;
    }
    for (; i < end; ++i) {
        int s = srcs[i];
        float e = LRELU(asrc[s * H1 + hh] + ad);
        float hv = h1[s * F_MID + lane];
        float mn = fmaxf(m, e);
        float sc = __expf(m - mn);
        float p  = __expf(e - mn);
        den = den * sc + p;
        acc = acc * sc + p * hv;
        m = mn;
    }
    float inv = 1.f / (den + 1e-16f);
    float v = acc * inv + b1[lane];
    out1[n * F_MID + lane] = v > 0.f ? v : expm1f(v);   // ELU
}

// ---------------- GEMM2: h2 = out1 @ W2  [N,64] x [64,41] ----------------
__global__ __launch_bounds__(256) void gemm2_kernel(
    const float* __restrict__ out1, const float* __restrict__ W2,
    float* __restrict__ h2, int N)
{
    __shared__ float ws[F_MID * NC];
    for (int i = threadIdx.x; i < F_MID * NC; i += 256) ws[i] = W2[i];
    __syncthreads();
    int idx = blockIdx.x * blockDim.x + threadIdx.x;
    if (idx >= N * NC) return;
    int n = idx / NC, j = idx % NC;
    const float* row = out1 + n * F_MID;
    float acc = 0.f;
    #pragma unroll
    for (int k = 0; k < F_MID; ++k) acc += row[k] * ws[k * NC + j];
    h2[idx] = acc;
}

__global__ void attn2_kernel(const float* __restrict__ h2,
                             const float* __restrict__ attS,
                             const float* __restrict__ attD,
                             float* __restrict__ asrc, float* __restrict__ adst, int N)
{
    int n = blockIdx.x * blockDim.x + threadIdx.x;
    if (n >= N) return;
    float s = 0.f, d = 0.f;
    #pragma unroll
    for (int j = 0; j < NC; ++j) {
        float v = h2[n * NC + j];
        s += v * attS[j];
        d += v * attD[j];
    }
    asrc[n] = s;
    adst[n] = d;
}

// ------- layer-2 aggregation + log_softmax: one wave per node, online softmax -------
__global__ void agg2_kernel(const int* __restrict__ offs, const int* __restrict__ srcs,
                            const float* __restrict__ h2,
                            const float* __restrict__ asrc, const float* __restrict__ adst,
                            const float* __restrict__ b2,
                            float* __restrict__ out, int N)
{
    int wave = (blockIdx.x * blockDim.x + threadIdx.x) >> 6;
    int lane = threadIdx.x & 63;
    if (wave >= N) return;
    int n = wave;
    int beg = offs[n], end = offs[n + 1];
    float ad = adst[n];
    bool act = lane < NC;

    float m = -INFINITY, den = 0.f, acc = 0.f;
    int i = beg;
    for (; i + 4 <= end; i += 4) {
        int s0 = srcs[i], s1 = srcs[i + 1], s2 = srcs[i + 2], s3 = srcs[i + 3];
        float a0 = asrc[s0], a1 = asrc[s1], a2 = asrc[s2], a3 = asrc[s3];
        float v0 = act ? h2[s0 * NC + lane] : 0.f;
        float v1 = act ? h2[s1 * NC + lane] : 0.f;
        float v2 = act ? h2[s2 * NC + lane] : 0.f;
        float v3 = act ? h2[s3 * NC + lane] : 0.f;
        float e0 = LRELU(a0 + ad), e1 = LRELU(a1 + ad);
        float e2 = LRELU(a2 + ad), e3 = LRELU(a3 + ad);
        float m4 = fmaxf(fmaxf(e0, e1), fmaxf(e2, e3));
        float mn = fmaxf(m, m4);
        float sc = __expf(m - mn);
        float p0 = __expf(e0 - mn), p1 = __expf(e1 - mn);
        float p2 = __expf(e2 - mn), p3 = __expf(e3 - mn);
        den = den * sc + ((p0 + p1) + (p2 + p3));
        acc = acc * sc + ((p0 * v0 + p1 * v1) + (p2 * v2 + p3 * v3));
        m = mn;
    }
    for (; i < end; ++i) {
        int s = srcs[i];
        float e = LRELU(asrc[s] + ad);
        float hv = act ? h2[s * NC + lane] : 0.f;
        float mn = fmaxf(m, e);
        float sc = __expf(m - mn);
        float p  = __expf(e - mn);
        den = den * sc + p;
        acc = acc * sc + p * hv;
        m = mn;
    }
    float inv = 1.f / (den + 1e-16f);
    float v = act ? acc * inv + b2[lane] : -INFINITY;
    float mm = v;
    #pragma unroll
    for (int o = 32; o > 0; o >>= 1) mm = fmaxf(mm, __shfl_xor(mm, o));
    float ex = act ? __expf(v - mm) : 0.f;
    float S = ex;
    #pragma unroll
    for (int o = 32; o > 0; o >>= 1) S += __shfl_xor(S, o);
    if (act) out[n * NC + lane] = v - mm - logf(S);
}

// ---------------- launch ----------------
extern "C" void kernel_launch(void* const* d_in, const int* in_sizes, int n_in,
                              void* d_out, int out_size, void* d_ws, size_t ws_size,
                              hipStream_t stream)
{
    const float* x     = (const float*)d_in[0];
    const int*   ei    = (const int*)  d_in[1];
    const float* W1    = (const float*)d_in[2];
    const float* attS1 = (const float*)d_in[3];
    const float* attD1 = (const float*)d_in[4];
    const float* b1    = (const float*)d_in[5];
    const float* W2    = (const float*)d_in[6];
    const float* attS2 = (const float*)d_in[7];
    const float* attD2 = (const float*)d_in[8];
    const float* b2    = (const float*)d_in[9];
    float* out = (float*)d_out;

    const int N = NN, E = NE;
    const int* src = ei;        // edge_index row 0
    const int* dst = ei + E;    // edge_index row 1

    char* p = (char*)d_ws;
    auto alloc = [&](size_t bytes) { char* r = p; p += (bytes + 255) & ~255ull; return r; };
    float* h1    = (float*)alloc((size_t)N * F_MID * 4);
    float* asrc1 = (float*)alloc((size_t)N * H1 * 4);
    float* adst1 = (float*)alloc((size_t)N * H1 * 4);
    float* out1  = (float*)alloc((size_t)N * F_MID * 4);
    float* h2    = (float*)alloc((size_t)N * NC * 4);
    float* asrc2 = (float*)alloc((size_t)N * 4);
    float* adst2 = (float*)alloc((size_t)N * 4);
    int*   deg   = (int*)alloc((size_t)2 * N * 4);    // deg + cursor contiguous
    int*   cursor= deg + N;
    int*   offs  = (int*)alloc((size_t)(N + 1) * 4);
    int*   srcs  = (int*)alloc((size_t)E * 4);
    unsigned short* Wt = (unsigned short*)alloc((size_t)F_MID * WT_LD * 2);
    const int NB = (N + 1023) / 1024;                 // 98 scan blocks
    int*   bsum  = (int*)alloc((size_t)NB * 4);
    int*   boff  = (int*)alloc((size_t)NB * 4);

    const int n4 = (2 * N) / 4;
    zero_kernel<<<(n4 + 255) / 256, 256, 0, stream>>>((int4*)deg, n4);

    prep_wt_kernel<<<(F_MID * WT_LD + 255) / 256, 256, 0, stream>>>(W1, Wt);
    gemm1_mfma<<<(N + 63) / 64, 256, 0, stream>>>(x, Wt, h1, N);
    attn1_kernel<<<(N * H1 + 255) / 256, 256, 0, stream>>>(h1, attS1, attD1, asrc1, adst1, N);
    deg_kernel<<<(E + 255) / 256, 256, 0, stream>>>(dst, deg, E);
    scan1_kernel<<<NB, 64, 0, stream>>>(deg, bsum, N);
    scan2_kernel<<<1, 128, 0, stream>>>(bsum, boff, NB, offs, N, E);
    scan3_kernel<<<NB, 64, 0, stream>>>(deg, boff, offs, N);
    scatter_kernel<<<(E + 255) / 256, 256, 0, stream>>>(src, dst, offs, cursor, srcs, E);
    agg1_kernel<<<(N * 64 + 255) / 256, 256, 0, stream>>>(offs, srcs, h1, asrc1, adst1, b1, out1, N);
    gemm2_kernel<<<(N * NC + 255) / 256, 256, 0, stream>>>(out1, W2, h2, N);
    attn2_kernel<<<(N + 255) / 256, 256, 0, stream>>>(h2, attS2, attD2, asrc2, adst2, N);
    agg2_kernel<<<(N * 64 + 255) / 256, 256, 0, stream>>>(offs, srcs, h2, asrc2, adst2, b2, out, N);
}